// Round 13
// baseline (21.744 us; speedup 1.0000x reference)
//
#include <hip/hip_runtime.h>
#include <stdint.h>

// NeRF "mark untrained cells": out[cas][m] = visible(cas, morton_decode(m)) ? density[cas][m] : -1
//
// Exact per-cell math (HW-validated bit-exact, rounds 3-12) + conservative per-wave SAT
// camera culling (rounds 10-12, absmax 0.0). Wave-count lever history: 32768->16384->8192
// ->4096 waves gave 24.0 -> 20.75 -> 17.8 -> 15.74 us. This round:
//  * 16 cells/thread: lane owns a 4x2x2 sub-box; wave = 1024 contiguous Morton cells
//    (16x8x8 box); waves -> 2048, blocks -> 512.
//  * visibility as three 16-bit lane masks (v0m/v1m/v2m) with per-cell tests INSIDE the
//    innermost unrolled loop -> low register pressure, all indices compile-time.
//  * dynamic cascade-done: when __all(vm==0xffff), strip cams needed only by that cascade
//    from the pending set (SGPR ops) -- kills tail iterations.
//  * load-skip epilogue: cascade with no visible cell wave-wide stores -1 without loading.
// Morton bits of 16*lane+s: x={s0,s3 | lane b2,b5}, y={s1 | lane b0,b3}, z={s2 | lane b1,b4}.

constexpr int GRIDN  = 128;
constexpr int NCELLS = GRIDN * GRIDN * GRIDN;   // 2097152
constexpr int NCAMS  = 32;
constexpr int BLOCK  = 256;
constexpr int CPB    = BLOCK * 16;              // 4096 cells per block

__device__ __forceinline__ uint32_t compact1by2(uint32_t x) {
    // inverse of reference _part1by2 (valid for 21-bit morton codes)
    x &= 0x09249249u;
    x = (x ^ (x >> 2))  & 0x030c30c3u;
    x = (x ^ (x >> 4))  & 0x0300f00fu;
    x = (x ^ (x >> 8))  & 0x030000ffu;
    x = (x ^ (x >> 16)) & 0x000003ffu;
    return x;
}

__launch_bounds__(BLOCK)
__global__ void nerf_mark_kernel(const float* __restrict__ dg,
                                 const float* __restrict__ poses,
                                 const float* __restrict__ intr,
                                 float* __restrict__ out) {
    // one 48B record per camera: R0..R8, dx, dy, dz  (16B aligned -> 3x ds_read_b128)
    __shared__ __align__(16) float sRd[NCAMS * 12];
    __shared__ float sc0[GRIDN];      // c0 table: round((2i/127 - 1) * S0)
    __shared__ float sax[2];          // cx/fx, cy/fy

    constexpr float S0  = 1.0f - 1.0f / 128.0f;   // 127/128, exact
    constexpr float T0  = 2.0f / 128.0f, T1 = 4.0f / 128.0f, T2 = 8.0f / 128.0f;
    constexpr float PAD = 1e-3f;                  // >> worst-case fp error (~4e-5)

    const int tid = threadIdx.x;
    for (int i = tid; i < NCAMS * 12; i += BLOCK) {   // 384 elems, 256 threads: strided
        int b = i / 12, k = i - b * 12;
        const float* P = poses + b * 16;
        if (k < 9) {
            sRd[i] = P[(k / 3) * 4 + (k % 3)];   // R[j][k']
        } else {
            int kk = k - 9;                       // (t.R)[kk], fma-chain rounding
            sRd[i] = fmaf(P[11], P[8 + kk], fmaf(P[7], P[4 + kk], P[3] * P[kk]));
        }
    }
    if (tid < GRIDN) {
        float w = (2.0f * (float)tid) / 127.0f - 1.0f;   // IEEE ufunc order
        sc0[tid] = __fmul_rn(w, S0);
    }
    if (tid == 0) { sax[0] = intr[2] / intr[0]; sax[1] = intr[3] / intr[1]; }
    __syncthreads();

    const int lane = tid & 63;
    const uint32_t wbase = (uint32_t)blockIdx.x * CPB + ((uint32_t)(tid >> 6)) * 1024u;

    // in-wave morton decode: cell = wbase + 16*lane + s, s in [0,16)
    // s = (xo&1) + 8*(xo>>1) + 2*yo + 4*zo ; lane gives the sub-box base
    const int xi = (((lane >> 2) & 1) << 2) | (((lane >> 5) & 1) << 3);
    const int yi = ((lane & 1) << 1) | (((lane >> 3) & 1) << 2);
    const int zi = (((lane >> 1) & 1) << 1) | (((lane >> 4) & 1) << 2);
    const int X0 = compact1by2(wbase);            // multiple of 16; wave x: X0..X0+15
    const int Y0 = compact1by2(wbase >> 1);       // multiple of 8
    const int Z0 = compact1by2(wbase >> 2);       // multiple of 8
    const float cxv[4] = { sc0[X0 + xi], sc0[X0 + xi + 1], sc0[X0 + xi + 2], sc0[X0 + xi + 3] };
    const float cyv[2] = { sc0[Y0 + yi], sc0[Y0 + yi + 1] };
    const float czv[2] = { sc0[Z0 + zi], sc0[Z0 + zi + 1] };
    const float ax = sax[0], ay = sax[1];

    // ---- phase 1: wave box (16x8x8 cells) center/halfwidth; sc0 monotonic ----
    const float gxl = sc0[X0], gxh = sc0[X0 + 15];
    const float gyl = sc0[Y0], gyh = sc0[Y0 + 7];
    const float gzl = sc0[Z0], gzh = sc0[Z0 + 7];
    const float gcx = 0.5f * (gxl + gxh), ghx = 0.5f * (gxh - gxl);
    const float gcy = 0.5f * (gyl + gyh), ghy = 0.5f * (gyh - gyl);
    const float gcz = 0.5f * (gzl + gzh), ghz = 0.5f * (gzh - gzl);

    // lane l classifies camera (l & 31) via 5-plane SAT (rounds 10-12 validated)
    const int cb = lane & 31;
    bool po0, in0, po1, in1, po2, in2;
    {
        const float4* A = reinterpret_cast<const float4*>(&sRd[cb * 12]);
        const float4 qa = A[0], qb = A[1], qc = A[2];
        const float ddx = qc.y, ddy = qc.z, ddz = qc.w;
        const float pcx = fmaf(gcz, qb.z, fmaf(gcy, qa.w, gcx * qa.x));
        const float pcy = fmaf(gcz, qb.w, fmaf(gcy, qb.x, gcx * qa.y));
        const float pcz = fmaf(gcz, qc.x, fmaf(gcy, qb.y, gcx * qa.z));
        // 5 linear forms: F0=z, F1=ax*z-x, F2=ax*z+x, F3=ay*z-y, F4=ay*z+y
        const float F1 = fmaf(ax, pcz, -pcx), F2 = fmaf(ax, pcz, pcx);
        const float F3 = fmaf(ay, pcz, -pcy), F4 = fmaf(ay, pcz, pcy);
        const float r0 = fmaf(ghz, fabsf(qc.x), fmaf(ghy, fabsf(qb.y), ghx * fabsf(qa.z)));
        const float a1x = fmaf(ax, qa.z, -qa.x), a1y = fmaf(ax, qb.y, -qa.w), a1z = fmaf(ax, qc.x, -qb.z);
        const float a2x = fmaf(ax, qa.z,  qa.x), a2y = fmaf(ax, qb.y,  qa.w), a2z = fmaf(ax, qc.x,  qb.z);
        const float a3x = fmaf(ay, qa.z, -qa.y), a3y = fmaf(ay, qb.y, -qb.x), a3z = fmaf(ay, qc.x, -qb.w);
        const float a4x = fmaf(ay, qa.z,  qa.y), a4y = fmaf(ay, qb.y,  qb.x), a4z = fmaf(ay, qc.x,  qb.w);
        const float r1 = fmaf(ghz, fabsf(a1z), fmaf(ghy, fabsf(a1y), ghx * fabsf(a1x)));
        const float r2 = fmaf(ghz, fabsf(a2z), fmaf(ghy, fabsf(a2y), ghx * fabsf(a2x)));
        const float r3 = fmaf(ghz, fabsf(a3z), fmaf(ghy, fabsf(a3y), ghx * fabsf(a3x)));
        const float r4 = fmaf(ghz, fabsf(a4z), fmaf(ghy, fabsf(a4y), ghx * fabsf(a4x)));
        const float e1 = fmaf(ax, ddz, -ddx), e2 = fmaf(ax, ddz, ddx);
        const float e3 = fmaf(ay, ddz, -ddy), e4 = fmaf(ay, ddz, ddy);

        auto classify = [&](float s, float T, bool& poss, bool& allin) {
            const float w0 = fmaf(s, pcz, -ddz);
            const float w1 = fmaf(s, F1, T - e1);
            const float w2 = fmaf(s, F2, T - e2);
            const float w3 = fmaf(s, F3, T - e3);
            const float w4 = fmaf(s, F4, T - e4);
            const float m0h = fmaf(s, r0, w0), m0l = fmaf(-s, r0, w0);
            const float m1h = fmaf(s, r1, w1), m1l = fmaf(-s, r1, w1);
            const float m2h = fmaf(s, r2, w2), m2l = fmaf(-s, r2, w2);
            const float m3h = fmaf(s, r3, w3), m3l = fmaf(-s, r3, w3);
            const float m4h = fmaf(s, r4, w4), m4l = fmaf(-s, r4, w4);
            poss  = !((m0h <= -PAD) | (m1h <= -PAD) | (m2h <= -PAD)
                                    | (m3h <= -PAD) | (m4h <= -PAD));
            allin = (m0l >= PAD) & (m1l >= PAD) & (m2l >= PAD)
                                 & (m3l >= PAD) & (m4l >= PAD);
        };
        classify(1.0f, T0, po0, in0);
        classify(2.0f, T1, po1, in1);
        classify(4.0f, T2, po2, in2);
    }

    const uint32_t allin0 = (uint32_t)__ballot(in0);
    const uint32_t allin1 = (uint32_t)__ballot(in1);
    const uint32_t allin2 = (uint32_t)__ballot(in2);
    const uint32_t poss0  = (uint32_t)__ballot(po0);
    const uint32_t poss1  = (uint32_t)__ballot(po1);
    const uint32_t poss2  = (uint32_t)__ballot(po2);

    const bool sat0 = (allin0 != 0u), sat1 = (allin1 != 0u), sat2 = (allin2 != 0u);
    uint32_t v0m = sat0 ? 0xffffu : 0u;   // per-lane 16-bit visibility masks, bit s
    uint32_t v1m = sat1 ? 0xffffu : 0u;
    uint32_t v2m = sat2 ? 0xffffu : 0u;
    bool d0 = sat0, d1 = sat1, d2 = sat2; // cascade complete wave-wide (uniform)

    // ---- phase 2: exact per-cell tests for silhouette cameras only ----
    const uint32_t u0 = sat0 ? 0u : poss0;
    const uint32_t u1 = sat1 ? 0u : poss1;
    const uint32_t u2 = sat2 ? 0u : poss2;
    uint32_t u = u0 | u1 | u2;
    while (u) {
        const int b = __ffs(u) - 1;
        const uint32_t bit = 1u << b;
        u &= u - 1;
        const float4* B = reinterpret_cast<const float4*>(&sRd[b * 12]);
        const float4 qa = B[0], qb = B[1], qc = B[2];
        const bool t0 = ((u0 & bit) != 0u) & !d0;   // wave-uniform -> scalar branches
        const bool t1 = ((u1 & bit) != 0u) & !d1;
        const bool t2 = ((u2 & bit) != 0u) & !d2;

        // per-cell chains, bit-exact validated form fmaf(cz,R2k, fmaf(cy,R1k, cx*R0k));
        // tests inside the innermost unrolled loop keep register pressure low.
        #pragma unroll
        for (int xo = 0; xo < 4; ++xo) {
            const float i0 = cxv[xo] * qa.x;
            const float i1 = cxv[xo] * qa.y;
            const float i2 = cxv[xo] * qa.z;
            #pragma unroll
            for (int yo = 0; yo < 2; ++yo) {
                const float j0 = fmaf(cyv[yo], qa.w, i0);
                const float j1 = fmaf(cyv[yo], qb.x, i1);
                const float j2 = fmaf(cyv[yo], qb.y, i2);
                #pragma unroll
                for (int zo = 0; zo < 2; ++zo) {
                    const int s = (xo & 1) + 8 * (xo >> 1) + 2 * yo + 4 * zo;
                    const uint32_t bs = 1u << s;
                    const float p0 = fmaf(czv[zo], qb.z, j0);
                    const float p1 = fmaf(czv[zo], qb.w, j1);
                    const float p2 = fmaf(czv[zo], qc.x, j2);
                    if (t0) {   // cascade 0: cam = p - d
                        const float zz = __fsub_rn(p2, qc.w);
                        const float xx = __fsub_rn(p0, qc.y);
                        const float yy = __fsub_rn(p1, qc.z);
                        const bool c = (zz > 0.0f)
                                     & (fabsf(xx) < __fadd_rn(__fmul_rn(ax, zz), T0))
                                     & (fabsf(yy) < __fadd_rn(__fmul_rn(ay, zz), T0));
                        v0m |= c ? bs : 0u;
                    }
                    if (t1) {   // cascade 1: cam = 2*p - d (exact pow2 scaling)
                        const float zz = fmaf(2.0f, p2, -qc.w);
                        const float xx = fmaf(2.0f, p0, -qc.y);
                        const float yy = fmaf(2.0f, p1, -qc.z);
                        const bool c = (zz > 0.0f)
                                     & (fabsf(xx) < __fadd_rn(__fmul_rn(ax, zz), T1))
                                     & (fabsf(yy) < __fadd_rn(__fmul_rn(ay, zz), T1));
                        v1m |= c ? bs : 0u;
                    }
                    if (t2) {   // cascade 2: cam = 4*p - d
                        const float zz = fmaf(4.0f, p2, -qc.w);
                        const float xx = fmaf(4.0f, p0, -qc.y);
                        const float yy = fmaf(4.0f, p1, -qc.z);
                        const bool c = (zz > 0.0f)
                                     & (fabsf(xx) < __fadd_rn(__fmul_rn(ax, zz), T2))
                                     & (fabsf(yy) < __fadd_rn(__fmul_rn(ay, zz), T2));
                        v2m |= c ? bs : 0u;
                    }
                }
            }
        }

        // dynamic cascade-done: strip cams needed only by completed cascades
        if (t0) d0 = __all(v0m == 0xffffu);
        if (t1) d1 = __all(v1m == 0xffffu);
        if (t2) d2 = __all(v2m == 0xffffu);
        u &= (d0 ? 0u : u0) | (d1 ? 0u : u1) | (d2 ? 0u : u2);
    }

    // ---- epilogue: 4x float4 per cascade; skip loads if cascade all-invisible ----
    const int mA = (int)(wbase + 16u * (uint32_t)lane);
    #pragma unroll
    for (int cas = 0; cas < 3; ++cas) {
        const uint32_t vm = (cas == 0) ? v0m : (cas == 1) ? v1m : v2m;
        const float* src = dg + cas * NCELLS + mA;
        float* dst = out + cas * NCELLS + mA;
        if (__any(vm != 0u)) {
            #pragma unroll
            for (int g = 0; g < 4; ++g) {
                const float4 d = *reinterpret_cast<const float4*>(src + 4 * g);
                float4 o;
                o.x = (vm & (1u << (4 * g + 0))) ? d.x : -1.0f;
                o.y = (vm & (1u << (4 * g + 1))) ? d.y : -1.0f;
                o.z = (vm & (1u << (4 * g + 2))) ? d.z : -1.0f;
                o.w = (vm & (1u << (4 * g + 3))) ? d.w : -1.0f;
                *reinterpret_cast<float4*>(dst + 4 * g) = o;
            }
        } else {
            const float4 neg = make_float4(-1.0f, -1.0f, -1.0f, -1.0f);
            #pragma unroll
            for (int g = 0; g < 4; ++g)
                *reinterpret_cast<float4*>(dst + 4 * g) = neg;
        }
    }
}

extern "C" void kernel_launch(void* const* d_in, const int* in_sizes, int n_in,
                              void* d_out, int out_size, void* d_ws, size_t ws_size,
                              hipStream_t stream) {
    const float* dg    = (const float*)d_in[0];   // (3, 128^3) f32
    const float* poses = (const float*)d_in[1];   // (32, 4, 4) f32
    const float* intr  = (const float*)d_in[2];   // (4,) f32
    float* out = (float*)d_out;                   // (3, 128^3) f32

    nerf_mark_kernel<<<NCELLS / CPB, BLOCK, 0, stream>>>(dg, poses, intr, out);
}

// Round 14
// 15.686 us; speedup vs baseline: 1.3862x; 1.3862x over previous
//
#include <hip/hip_runtime.h>
#include <stdint.h>

// NeRF "mark untrained cells": out[cas][m] = visible(cas, morton_decode(m)) ? density[cas][m] : -1
//
// Structure = round 12 (VALIDATED 15.74us, absmax 0.0): 8 cells/thread (2x2x2 per lane),
// wave = 8x8x8 box, 4096 waves, 1024 blocks x 256 threads. Round 13 (16 cells, 2048 waves)
// REGRESSED to 21.7us -- wave-count lever exhausted; reverted.
// Grafts this round (orthogonal, were never isolated in r13):
//  * dynamic cascade-done stripping: when __all(vm==0xff) for a cascade, remove cams
//    pending only for it from the silhouette set (wave-uniform SGPR ops).
//  * load-skip epilogue: cascade with no visible cell wave-wide stores -1 without
//    reading dg (~2/3 of chunks) -> less fetch traffic + no vmem latency there.
// Exact per-cell math HW-validated bit-exact rounds 3-12; SAT classifier rounds 10-12.

constexpr int GRIDN  = 128;
constexpr int NCELLS = GRIDN * GRIDN * GRIDN;   // 2097152
constexpr int NCAMS  = 32;
constexpr int BLOCK  = 256;
constexpr int CPB    = BLOCK * 8;               // 2048 cells per block

__device__ __forceinline__ uint32_t compact1by2(uint32_t x) {
    // inverse of reference _part1by2 (valid for 21-bit morton codes)
    x &= 0x09249249u;
    x = (x ^ (x >> 2))  & 0x030c30c3u;
    x = (x ^ (x >> 4))  & 0x0300f00fu;
    x = (x ^ (x >> 8))  & 0x030000ffu;
    x = (x ^ (x >> 16)) & 0x000003ffu;
    return x;
}

__launch_bounds__(BLOCK)
__global__ void nerf_mark_kernel(const float* __restrict__ dg,
                                 const float* __restrict__ poses,
                                 const float* __restrict__ intr,
                                 float* __restrict__ out) {
    // one 48B record per camera: R0..R8, dx, dy, dz  (16B aligned -> 3x ds_read_b128)
    __shared__ __align__(16) float sRd[NCAMS * 12];
    __shared__ float sc0[GRIDN];      // c0 table: round((2i/127 - 1) * S0)
    __shared__ float sax[2];          // cx/fx, cy/fy

    constexpr float S0  = 1.0f - 1.0f / 128.0f;   // 127/128, exact
    constexpr float T0  = 2.0f / 128.0f, T1 = 4.0f / 128.0f, T2 = 8.0f / 128.0f;
    constexpr float PAD = 1e-3f;                  // >> worst-case fp error (~4e-5)

    const int tid = threadIdx.x;
    for (int i = tid; i < NCAMS * 12; i += BLOCK) {   // 384 elems, 256 threads: strided
        int b = i / 12, k = i - b * 12;
        const float* P = poses + b * 16;
        if (k < 9) {
            sRd[i] = P[(k / 3) * 4 + (k % 3)];   // R[j][k']
        } else {
            int kk = k - 9;                       // (t.R)[kk], fma-chain rounding
            sRd[i] = fmaf(P[11], P[8 + kk], fmaf(P[7], P[4 + kk], P[3] * P[kk]));
        }
    }
    if (tid < GRIDN) {
        float w = (2.0f * (float)tid) / 127.0f - 1.0f;   // IEEE ufunc order
        sc0[tid] = __fmul_rn(w, S0);
    }
    if (tid == 0) { sax[0] = intr[2] / intr[0]; sax[1] = intr[3] / intr[1]; }
    __syncthreads();

    const int lane = tid & 63;
    const uint32_t wbase = (uint32_t)blockIdx.x * CPB + ((uint32_t)(tid >> 6)) * 512u;

    // in-wave morton decode: cell = wbase + 8*lane + s, s in [0,8)
    const int xi = ((lane & 1) << 1) | (((lane >> 3) & 1) << 2);
    const int yi = (((lane >> 1) & 1) << 1) | (((lane >> 4) & 1) << 2);
    const int zi = (((lane >> 2) & 1) << 1) | (((lane >> 5) & 1) << 2);
    const int X0 = compact1by2(wbase);            // multiple of 8; wave box x: X0..X0+7
    const int Y0 = compact1by2(wbase >> 1);       // multiple of 8
    const int Z0 = compact1by2(wbase >> 2);       // multiple of 8
    const float cxv[2] = { sc0[X0 + xi], sc0[X0 + xi + 1] };
    const float cyv[2] = { sc0[Y0 + yi], sc0[Y0 + yi + 1] };
    const float czv[2] = { sc0[Z0 + zi], sc0[Z0 + zi + 1] };
    const float ax = sax[0], ay = sax[1];

    // ---- phase 1: wave box (8x8x8 cells) center/halfwidth; sc0 monotonic ----
    const float gxl = sc0[X0], gxh = sc0[X0 + 7];
    const float gyl = sc0[Y0], gyh = sc0[Y0 + 7];
    const float gzl = sc0[Z0], gzh = sc0[Z0 + 7];
    const float gcx = 0.5f * (gxl + gxh), ghx = 0.5f * (gxh - gxl);
    const float gcy = 0.5f * (gyl + gyh), ghy = 0.5f * (gyh - gyl);
    const float gcz = 0.5f * (gzl + gzh), ghz = 0.5f * (gzh - gzl);

    // lane l classifies camera (l & 31) via 5-plane SAT (rounds 10-12 validated)
    const int cb = lane & 31;
    bool po0, in0, po1, in1, po2, in2;
    {
        const float4* A = reinterpret_cast<const float4*>(&sRd[cb * 12]);
        const float4 qa = A[0], qb = A[1], qc = A[2];
        const float ddx = qc.y, ddy = qc.z, ddz = qc.w;
        const float pcx = fmaf(gcz, qb.z, fmaf(gcy, qa.w, gcx * qa.x));
        const float pcy = fmaf(gcz, qb.w, fmaf(gcy, qb.x, gcx * qa.y));
        const float pcz = fmaf(gcz, qc.x, fmaf(gcy, qb.y, gcx * qa.z));
        // 5 linear forms: F0=z, F1=ax*z-x, F2=ax*z+x, F3=ay*z-y, F4=ay*z+y
        const float F1 = fmaf(ax, pcz, -pcx), F2 = fmaf(ax, pcz, pcx);
        const float F3 = fmaf(ay, pcz, -pcy), F4 = fmaf(ay, pcz, pcy);
        const float r0 = fmaf(ghz, fabsf(qc.x), fmaf(ghy, fabsf(qb.y), ghx * fabsf(qa.z)));
        const float a1x = fmaf(ax, qa.z, -qa.x), a1y = fmaf(ax, qb.y, -qa.w), a1z = fmaf(ax, qc.x, -qb.z);
        const float a2x = fmaf(ax, qa.z,  qa.x), a2y = fmaf(ax, qb.y,  qa.w), a2z = fmaf(ax, qc.x,  qb.z);
        const float a3x = fmaf(ay, qa.z, -qa.y), a3y = fmaf(ay, qb.y, -qb.x), a3z = fmaf(ay, qc.x, -qb.w);
        const float a4x = fmaf(ay, qa.z,  qa.y), a4y = fmaf(ay, qb.y,  qb.x), a4z = fmaf(ay, qc.x,  qb.w);
        const float r1 = fmaf(ghz, fabsf(a1z), fmaf(ghy, fabsf(a1y), ghx * fabsf(a1x)));
        const float r2 = fmaf(ghz, fabsf(a2z), fmaf(ghy, fabsf(a2y), ghx * fabsf(a2x)));
        const float r3 = fmaf(ghz, fabsf(a3z), fmaf(ghy, fabsf(a3y), ghx * fabsf(a3x)));
        const float r4 = fmaf(ghz, fabsf(a4z), fmaf(ghy, fabsf(a4y), ghx * fabsf(a4x)));
        const float e1 = fmaf(ax, ddz, -ddx), e2 = fmaf(ax, ddz, ddx);
        const float e3 = fmaf(ay, ddz, -ddy), e4 = fmaf(ay, ddz, ddy);

        auto classify = [&](float s, float T, bool& poss, bool& allin) {
            const float w0 = fmaf(s, pcz, -ddz);
            const float w1 = fmaf(s, F1, T - e1);
            const float w2 = fmaf(s, F2, T - e2);
            const float w3 = fmaf(s, F3, T - e3);
            const float w4 = fmaf(s, F4, T - e4);
            const float m0h = fmaf(s, r0, w0), m0l = fmaf(-s, r0, w0);
            const float m1h = fmaf(s, r1, w1), m1l = fmaf(-s, r1, w1);
            const float m2h = fmaf(s, r2, w2), m2l = fmaf(-s, r2, w2);
            const float m3h = fmaf(s, r3, w3), m3l = fmaf(-s, r3, w3);
            const float m4h = fmaf(s, r4, w4), m4l = fmaf(-s, r4, w4);
            poss  = !((m0h <= -PAD) | (m1h <= -PAD) | (m2h <= -PAD)
                                    | (m3h <= -PAD) | (m4h <= -PAD));
            allin = (m0l >= PAD) & (m1l >= PAD) & (m2l >= PAD)
                                 & (m3l >= PAD) & (m4l >= PAD);
        };
        classify(1.0f, T0, po0, in0);
        classify(2.0f, T1, po1, in1);
        classify(4.0f, T2, po2, in2);
    }

    const uint32_t allin0 = (uint32_t)__ballot(in0);
    const uint32_t allin1 = (uint32_t)__ballot(in1);
    const uint32_t allin2 = (uint32_t)__ballot(in2);
    const uint32_t poss0  = (uint32_t)__ballot(po0);
    const uint32_t poss1  = (uint32_t)__ballot(po1);
    const uint32_t poss2  = (uint32_t)__ballot(po2);

    const bool sat0 = (allin0 != 0u), sat1 = (allin1 != 0u), sat2 = (allin2 != 0u);
    // per-lane 8-bit visibility masks; cell s = x + 2y + 4z (memory order 8*lane+s)
    uint32_t v0m = sat0 ? 0xffu : 0u;
    uint32_t v1m = sat1 ? 0xffu : 0u;
    uint32_t v2m = sat2 ? 0xffu : 0u;
    bool d0 = sat0, d1 = sat1, d2 = sat2;   // cascade done wave-wide (uniform)

    // ---- phase 2: exact per-cell tests for silhouette cameras only ----
    const uint32_t u0 = sat0 ? 0u : poss0;
    const uint32_t u1 = sat1 ? 0u : poss1;
    const uint32_t u2 = sat2 ? 0u : poss2;
    uint32_t u = u0 | u1 | u2;
    while (u) {
        const int b = __ffs(u) - 1;
        const uint32_t bit = 1u << b;
        u &= u - 1;
        const float4* B = reinterpret_cast<const float4*>(&sRd[b * 12]);
        const float4 qa = B[0], qb = B[1], qc = B[2];
        const bool t0 = ((u0 & bit) != 0u) & !d0;   // wave-uniform -> scalar branches
        const bool t1 = ((u1 & bit) != 0u) & !d1;
        const bool t2 = ((u2 & bit) != 0u) & !d2;

        // 8 cells share chain prefixes; each cell's full chain is the bit-exact
        // validated sequence fmaf(cz, R2k, fmaf(cy, R1k, cx*R0k)).
        float p0[8], p1[8], p2[8];
        #pragma unroll
        for (int x = 0; x < 2; ++x) {
            const float i0 = cxv[x] * qa.x;
            const float i1 = cxv[x] * qa.y;
            const float i2 = cxv[x] * qa.z;
            #pragma unroll
            for (int y = 0; y < 2; ++y) {
                const float j0 = fmaf(cyv[y], qa.w, i0);
                const float j1 = fmaf(cyv[y], qb.x, i1);
                const float j2 = fmaf(cyv[y], qb.y, i2);
                #pragma unroll
                for (int z = 0; z < 2; ++z) {
                    const int s = x + 2 * y + 4 * z;
                    p0[s] = fmaf(czv[z], qb.z, j0);
                    p1[s] = fmaf(czv[z], qb.w, j1);
                    p2[s] = fmaf(czv[z], qc.x, j2);
                }
            }
        }

        if (t0) {   // cascade 0: cam = p - d
            #pragma unroll
            for (int s = 0; s < 8; ++s) {
                const float zz = __fsub_rn(p2[s], qc.w);
                const float xx = __fsub_rn(p0[s], qc.y);
                const float yy = __fsub_rn(p1[s], qc.z);
                const bool c = (zz > 0.0f)
                             & (fabsf(xx) < __fadd_rn(__fmul_rn(ax, zz), T0))
                             & (fabsf(yy) < __fadd_rn(__fmul_rn(ay, zz), T0));
                v0m |= c ? (1u << s) : 0u;
            }
            d0 = __all(v0m == 0xffu);
        }
        if (t1) {   // cascade 1: cam = 2*p - d (exact pow2 scaling)
            #pragma unroll
            for (int s = 0; s < 8; ++s) {
                const float zz = fmaf(2.0f, p2[s], -qc.w);
                const float xx = fmaf(2.0f, p0[s], -qc.y);
                const float yy = fmaf(2.0f, p1[s], -qc.z);
                const bool c = (zz > 0.0f)
                             & (fabsf(xx) < __fadd_rn(__fmul_rn(ax, zz), T1))
                             & (fabsf(yy) < __fadd_rn(__fmul_rn(ay, zz), T1));
                v1m |= c ? (1u << s) : 0u;
            }
            d1 = __all(v1m == 0xffu);
        }
        if (t2) {   // cascade 2: cam = 4*p - d
            #pragma unroll
            for (int s = 0; s < 8; ++s) {
                const float zz = fmaf(4.0f, p2[s], -qc.w);
                const float xx = fmaf(4.0f, p0[s], -qc.y);
                const float yy = fmaf(4.0f, p1[s], -qc.z);
                const bool c = (zz > 0.0f)
                             & (fabsf(xx) < __fadd_rn(__fmul_rn(ax, zz), T2))
                             & (fabsf(yy) < __fadd_rn(__fmul_rn(ay, zz), T2));
                v2m |= c ? (1u << s) : 0u;
            }
            d2 = __all(v2m == 0xffu);
        }

        // dynamic cascade-done stripping: drop cams pending only for finished cascades
        u &= (d0 ? 0u : u0) | (d1 ? 0u : u1) | (d2 ? 0u : u2);
    }

    // ---- epilogue: 2x float4 per cascade; skip dg loads if cascade all-invisible ----
    const int mA = (int)(wbase + 8u * (uint32_t)lane);
    #pragma unroll
    for (int cas = 0; cas < 3; ++cas) {
        const uint32_t vm = (cas == 0) ? v0m : (cas == 1) ? v1m : v2m;
        const float* src = dg + cas * NCELLS + mA;
        float* dst = out + cas * NCELLS + mA;
        if (__any(vm != 0u)) {
            const float4 dlo = *reinterpret_cast<const float4*>(src);
            const float4 dhi = *reinterpret_cast<const float4*>(src + 4);
            float4 olo, ohi;
            olo.x = (vm & 0x01u) ? dlo.x : -1.0f; olo.y = (vm & 0x02u) ? dlo.y : -1.0f;
            olo.z = (vm & 0x04u) ? dlo.z : -1.0f; olo.w = (vm & 0x08u) ? dlo.w : -1.0f;
            ohi.x = (vm & 0x10u) ? dhi.x : -1.0f; ohi.y = (vm & 0x20u) ? dhi.y : -1.0f;
            ohi.z = (vm & 0x40u) ? dhi.z : -1.0f; ohi.w = (vm & 0x80u) ? dhi.w : -1.0f;
            *reinterpret_cast<float4*>(dst)     = olo;
            *reinterpret_cast<float4*>(dst + 4) = ohi;
        } else {
            const float4 neg = make_float4(-1.0f, -1.0f, -1.0f, -1.0f);
            *reinterpret_cast<float4*>(dst)     = neg;
            *reinterpret_cast<float4*>(dst + 4) = neg;
        }
    }
}

extern "C" void kernel_launch(void* const* d_in, const int* in_sizes, int n_in,
                              void* d_out, int out_size, void* d_ws, size_t ws_size,
                              hipStream_t stream) {
    const float* dg    = (const float*)d_in[0];   // (3, 128^3) f32
    const float* poses = (const float*)d_in[1];   // (32, 4, 4) f32
    const float* intr  = (const float*)d_in[2];   // (4,) f32
    float* out = (float*)d_out;                   // (3, 128^3) f32

    nerf_mark_kernel<<<NCELLS / CPB, BLOCK, 0, stream>>>(dg, poses, intr, out);
}